// Round 4
// baseline (667.616 us; speedup 1.0000x reference)
//
#include <hip/hip_runtime.h>

#define B_   4
#define C_   64
#define HW_  4096
#define D_   576      // C * 3 * 3
#define L_   961      // 31 * 31 keys
#define LP_  1024     // padded L (zero-filled)
#define LAMDA_ 10.0f
#define EPS_   1e-6f

typedef short short8 __attribute__((ext_vector_type(8)));
typedef float f32x16 __attribute__((ext_vector_type(16)));
typedef unsigned short u16;

// round-to-nearest-even f32 -> bf16 bits
__device__ __forceinline__ u16 f2bf(float x) {
    unsigned u = __float_as_uint(x);
    u += 0x7FFFu + ((u >> 16) & 1u);
    return (u16)(u >> 16);
}
__device__ __forceinline__ float bf2f(u16 h) {
    return __uint_as_float(((unsigned)h) << 16);
}
// D = A*B + D, 32x32x16 bf16. Inline asm: avoids builtin signature ambiguity.
// A frag: lane holds A[lane&31][8*(lane>>5)+i], i=0..7 (16B contiguous along k)
// B frag: lane holds B[8*(lane>>5)+i][lane&31]  (k-contiguous per column)
// D frag: reg r -> D[(r&3)+8*(r>>2)+4*(lane>>5)][lane&31]   [verified mapping]
__device__ __forceinline__ void mfma_bf16(f32x16& d, short8 a, short8 b) {
    asm volatile("v_mfma_f32_32x32x16_bf16 %0, %1, %2, %0"
                 : "+v"(d) : "v"(a), "v"(b));
}

// ---------------------------------------------------------------------------
// UB[b][d][l] (d-major) hi/lo: ub = bg_in*mask unfolded (k=3, s=2, pad=0)
// ---------------------------------------------------------------------------
__global__ __launch_bounds__(256) void fill_ub_kernel(const float* __restrict__ bg_in,
                                                      const float* __restrict__ mask,
                                                      u16* __restrict__ UBh,
                                                      u16* __restrict__ UBl) {
    int idx = blockIdx.x * 256 + threadIdx.x;     // b*D_*LP_ + d*LP_ + l
    int b   = idx / (D_ * LP_);
    int rem = idx - b * (D_ * LP_);
    int d   = rem >> 10;
    int l   = idx & (LP_ - 1);
    float v = 0.f;
    if (l < L_) {
        int ly = l / 31, lx = l - ly * 31;
        int c  = d / 9,  kk = d - c * 9;
        int i  = kk / 3, j  = kk - i * 3;
        int pix = ((2 * ly + i) << 6) + 2 * lx + j;
        v = bg_in[((b * C_ + c) << 12) + pix] * mask[(b << 12) + pix];
    }
    u16 h = f2bf(v);
    UBh[idx] = h;
    UBl[idx] = f2bf(v - bf2f(h));
}

// UBT[b][l][d] (l-major) hi/lo — same values, transposed layout for GEMM1 B.
__global__ __launch_bounds__(256) void fill_ubT_kernel(const float* __restrict__ bg_in,
                                                       const float* __restrict__ mask,
                                                       u16* __restrict__ UBTh,
                                                       u16* __restrict__ UBTl) {
    int idx = blockIdx.x * 256 + threadIdx.x;     // (b*LP_ + l)*D_ + d
    int d   = idx % D_;
    int tmp = idx / D_;
    int l   = tmp & (LP_ - 1);
    int b   = tmp >> 10;
    float v = 0.f;
    if (l < L_) {
        int ly = l / 31, lx = l - ly * 31;
        int c  = d / 9,  kk = d - c * 9;
        int i  = kk / 3, j  = kk - i * 3;
        int pix = ((2 * ly + i) << 6) + 2 * lx + j;
        v = bg_in[((b * C_ + c) << 12) + pix] * mask[(b << 12) + pix];
    }
    u16 h = f2bf(v);
    UBTh[idx] = h;
    UBTl[idx] = f2bf(v - bf2f(h));
}

// K1D[b][l] += partial sum over 144 d's of (hi+lo)^2
__global__ __launch_bounds__(256) void k1d_kernel(const u16* __restrict__ UBh,
                                                  const u16* __restrict__ UBl,
                                                  float* __restrict__ K1D) {
    int t = blockIdx.x * 256 + threadIdx.x;       // b*1024 + l
    int b = t >> 10;
    int l = t & 1023;
    size_t base = (size_t)b * (D_ * LP_) + (size_t)(blockIdx.y * 144) * LP_ + l;
    float s = 0.f;
    #pragma unroll 8
    for (int d = 0; d < 144; ++d) {
        float v = bf2f(UBh[base + (size_t)d * LP_]) + bf2f(UBl[base + (size_t)d * LP_]);
        s += v * v;
    }
    atomicAdd(&K1D[t], s);
}

// WW[b][p][d] hi/lo = fg unfolded (k=3, s=1, pad=1) — query patches
__global__ __launch_bounds__(256) void fill_ww_kernel(const float* __restrict__ fg,
                                                      u16* __restrict__ WWh,
                                                      u16* __restrict__ WWl) {
    int idx = blockIdx.x * 256 + threadIdx.x;     // (b*HW + p)*D + d
    int d   = idx % D_;
    int tmp = idx / D_;
    int p   = tmp & 4095;
    int b   = tmp >> 12;
    int c   = d / 9,  kk = d - c * 9;
    int i   = kk / 3, j  = kk - i * 3;
    int y   = (p >> 6) + i - 1, x = (p & 63) + j - 1;
    float v = 0.f;
    if ((unsigned)y < 64u && (unsigned)x < 64u)
        v = fg[((b * C_ + c) << 12) + (y << 6) + x];
    u16 h = f2bf(v);
    WWh[idx] = h;
    WWl[idx] = f2bf(v - bf2f(h));
}

// P[b][p] = sum_c fg^2 (exact f32)
__global__ __launch_bounds__(256) void pixsq_kernel(const float* __restrict__ fg,
                                                    float* __restrict__ P) {
    int t = blockIdx.x * 256 + threadIdx.x;
    int b = t >> 12, p = t & 4095;
    const float* base = fg + ((size_t)(b * C_) << 12) + p;
    float s = 0.f;
    #pragma unroll 8
    for (int c = 0; c < C_; ++c) { float v = base[c << 12]; s += v * v; }
    P[t] = s;
}

// ---------------------------------------------------------------------------
// GEMM1: CS[b][q][l] = sum_d WW[q][d]*UB[d][l], bf16x3 MFMA 32x32x16.
// Block 128x128, 4 waves (2x2), wave = 64x64 = 2x2 frags of 32x32.
// LDS: [q=k/8][row][8] 16B blocks (sequential-16B: conflict-free).
// ---------------------------------------------------------------------------
__global__ __launch_bounds__(256) void gemm1_kernel(
    const u16* __restrict__ WWh, const u16* __restrict__ WWl,
    const u16* __restrict__ UBTh, const u16* __restrict__ UBTl,
    float* __restrict__ CS)
{
    int b = blockIdx.z;
    const u16* Ahg = WWh  + (size_t)b * HW_ * D_;
    const u16* Alg = WWl  + (size_t)b * HW_ * D_;
    const u16* Bhg = UBTh + (size_t)b * LP_ * D_;
    const u16* Blg = UBTl + (size_t)b * LP_ * D_;
    float* C = CS + (size_t)b * HW_ * LP_;
    int n0 = blockIdx.x << 7, m0 = blockIdx.y << 7;

    __shared__ __align__(16) u16 Ah[4096], Al[4096], Bh[4096], Bl[4096];

    int t = threadIdx.x;
    int lane = t & 63;
    int w = t >> 6, wm = w >> 1, wn = w & 1;
    int lr = lane & 31, lk = lane >> 5;

    f32x16 acc[2][2];
    #pragma unroll
    for (int i = 0; i < 2; ++i)
        #pragma unroll
        for (int j = 0; j < 2; ++j)
            #pragma unroll
            for (int r = 0; r < 16; ++r) acc[i][j][r] = 0.f;

    for (int k0 = 0; k0 < D_; k0 += 32) {
        __syncthreads();
        #pragma unroll
        for (int i = 0; i < 2; ++i) {                 // 512 16B slots / matrix
            int lin = i * 256 + t;
            int q = lin >> 7, r = lin & 127;
            size_t ga = (size_t)(m0 + r) * D_ + k0 + q * 8;
            size_t gb = (size_t)(n0 + r) * D_ + k0 + q * 8;
            *(uint4*)&Ah[lin * 8] = *(const uint4*)(Ahg + ga);
            *(uint4*)&Al[lin * 8] = *(const uint4*)(Alg + ga);
            *(uint4*)&Bh[lin * 8] = *(const uint4*)(Bhg + gb);
            *(uint4*)&Bl[lin * 8] = *(const uint4*)(Blg + gb);
        }
        __syncthreads();
        #pragma unroll
        for (int kh = 0; kh < 2; ++kh) {
            int qq = kh * 2 + lk;
            short8 ah[2], al[2], bhf[2], blf[2];
            #pragma unroll
            for (int f = 0; f < 2; ++f) {
                int ra = (qq * 128 + wm * 64 + f * 32 + lr) * 8;
                int rb = (qq * 128 + wn * 64 + f * 32 + lr) * 8;
                ah[f]  = *(const short8*)&Ah[ra];
                al[f]  = *(const short8*)&Al[ra];
                bhf[f] = *(const short8*)&Bh[rb];
                blf[f] = *(const short8*)&Bl[rb];
            }
            #pragma unroll
            for (int fm = 0; fm < 2; ++fm)
                #pragma unroll
                for (int fn = 0; fn < 2; ++fn)
                    mfma_bf16(acc[fm][fn], ah[fm], bhf[fn]);
            #pragma unroll
            for (int fm = 0; fm < 2; ++fm)
                #pragma unroll
                for (int fn = 0; fn < 2; ++fn)
                    mfma_bf16(acc[fm][fn], ah[fm], blf[fn]);
            #pragma unroll
            for (int fm = 0; fm < 2; ++fm)
                #pragma unroll
                for (int fn = 0; fn < 2; ++fn)
                    mfma_bf16(acc[fm][fn], al[fm], bhf[fn]);
        }
    }
    #pragma unroll
    for (int fm = 0; fm < 2; ++fm)
        #pragma unroll
        for (int fn = 0; fn < 2; ++fn) {
            int colb = n0 + wn * 64 + fn * 32 + lr;
            int rowb = m0 + wm * 64 + fm * 32 + 4 * lk;
            #pragma unroll
            for (int r = 0; r < 16; ++r) {
                int row = rowb + (r & 3) + 8 * (r >> 2);
                C[(size_t)row * LP_ + colb] = acc[fm][fn][r];
            }
        }
}

// ---------------------------------------------------------------------------
// Row stats + tanh + softmax. Reads f32 CS row, writes bf16 hi/lo IN PLACE
// over the same row: u16 layout [hi 0..1023 | lo 1024..2047]. Pads -> 0.
// ---------------------------------------------------------------------------
__device__ __forceinline__ float block_reduce_sum(float v, float* sred) {
    #pragma unroll
    for (int m = 32; m > 0; m >>= 1) v += __shfl_xor(v, m, 64);
    __syncthreads();
    if ((threadIdx.x & 63) == 0) sred[threadIdx.x >> 6] = v;
    __syncthreads();
    return sred[0] + sred[1] + sred[2] + sred[3];
}

__global__ __launch_bounds__(256) void stats_softmax_kernel(float* __restrict__ CA,
                                                            const float* __restrict__ K1D,
                                                            const float* __restrict__ P) {
    __shared__ float sred[4];
    int row = blockIdx.x;                         // b*4096 + q
    int b = row >> 12, q = row & 4095;
    int h = q >> 6, wx = q & 63;
    float wwd = 0.f;
    #pragma unroll
    for (int i = 0; i < 3; ++i)
        #pragma unroll
        for (int j = 0; j < 3; ++j) {
            int y = h + i - 1, x = wx + j - 1;
            if ((unsigned)y < 64u && (unsigned)x < 64u)
                wwd += P[(b << 12) + (y << 6) + x];
        }
    float* cs = CA + (size_t)row * LP_;
    u16* ch = (u16*)cs;                           // in-place overlay
    const float* k1 = K1D + (b << 10);
    int t = threadIdx.x;
    float xv[4];
    float lsum = 0.f;
    #pragma unroll
    for (int i = 0; i < 4; ++i) {
        int l = t + (i << 8);
        float ds = 0.f;
        if (l < L_) ds = k1[l] + wwd - 2.f * cs[l];
        xv[i] = ds;
        lsum += ds;
    }
    float mean = block_reduce_sum(lsum, sred) * (1.f / 961.f);
    float lvar = 0.f;
    #pragma unroll
    for (int i = 0; i < 4; ++i) {
        int l = t + (i << 8);
        if (l < L_) { float dd = xv[i] - mean; lvar += dd * dd; }
    }
    float var = block_reduce_sum(lvar, sred) * (1.f / 961.f);
    float inv = 1.f / (sqrtf(var) + EPS_);
    float ev[4];
    float lsume = 0.f;
    #pragma unroll
    for (int i = 0; i < 4; ++i) {
        int l = t + (i << 8);
        float e = 0.f;
        if (l < L_) e = expf(-LAMDA_ * tanhf((xv[i] - mean) * inv));
        ev[i] = e;
        lsume += e;
    }
    float rs = 1.f / block_reduce_sum(lsume, sred);
    #pragma unroll
    for (int i = 0; i < 4; ++i) {                 // all reads done (barriers above)
        int l2 = t + (i << 8);
        float v = ev[i] * rs;                     // pad -> exact 0
        u16 hi = f2bf(v);
        ch[l2]        = hi;
        ch[1024 + l2] = f2bf(v - bf2f(hi));
    }
}

// ---------------------------------------------------------------------------
// GEMM2: ET[b][d][q] = sum_l UB[d][l]*CA[q][l], bf16x3 MFMA (NT: both k-contig).
// Block 64x256, 4 waves (1x4), wave = 64x64 = 2x2 frags of 32x32.
// ---------------------------------------------------------------------------
__global__ __launch_bounds__(256) void gemm2_kernel(
    const u16* __restrict__ UBh, const u16* __restrict__ UBl,
    const float* __restrict__ CAbase, float* __restrict__ ET)
{
    int b = blockIdx.z;
    const u16* Ahg = UBh + (size_t)b * D_ * LP_;
    const u16* Alg = UBl + (size_t)b * D_ * LP_;
    const u16* CAB = (const u16*)(CAbase + (size_t)b * HW_ * LP_);   // rows: 2048 u16
    float* C = ET + (size_t)b * D_ * HW_;
    int n0 = blockIdx.x << 8, m0 = blockIdx.y << 6;

    __shared__ __align__(16) u16 Ah[2048], Al[2048], Bh[8192], Bl[8192];

    int t = threadIdx.x;
    int lane = t & 63;
    int w = t >> 6;
    int lr = lane & 31, lk = lane >> 5;

    f32x16 acc[2][2];
    #pragma unroll
    for (int i = 0; i < 2; ++i)
        #pragma unroll
        for (int j = 0; j < 2; ++j)
            #pragma unroll
            for (int r = 0; r < 16; ++r) acc[i][j][r] = 0.f;

    for (int k0 = 0; k0 < LP_; k0 += 32) {
        __syncthreads();
        {                                             // A: 256 slots
            int q = t >> 6, r = t & 63;
            size_t ga = (size_t)(m0 + r) * LP_ + k0 + q * 8;
            *(uint4*)&Ah[t * 8] = *(const uint4*)(Ahg + ga);
            *(uint4*)&Al[t * 8] = *(const uint4*)(Alg + ga);
        }
        #pragma unroll
        for (int i = 0; i < 4; ++i) {                 // B: 1024 slots
            int lin = i * 256 + t;
            int q = lin >> 8, r = lin & 255;
            size_t gb = (size_t)(n0 + r) * 2048 + k0 + q * 8;
            *(uint4*)&Bh[lin * 8] = *(const uint4*)(CAB + gb);
            *(uint4*)&Bl[lin * 8] = *(const uint4*)(CAB + gb + 1024);
        }
        __syncthreads();
        #pragma unroll
        for (int kh = 0; kh < 2; ++kh) {
            int qq = kh * 2 + lk;
            short8 ah[2], al[2], bhf[2], blf[2];
            #pragma unroll
            for (int f = 0; f < 2; ++f) {
                int ra = (qq * 64 + f * 32 + lr) * 8;
                int rb = (qq * 256 + w * 64 + f * 32 + lr) * 8;
                ah[f]  = *(const short8*)&Ah[ra];
                al[f]  = *(const short8*)&Al[ra];
                bhf[f] = *(const short8*)&Bh[rb];
                blf[f] = *(const short8*)&Bl[rb];
            }
            #pragma unroll
            for (int fm = 0; fm < 2; ++fm)
                #pragma unroll
                for (int fn = 0; fn < 2; ++fn)
                    mfma_bf16(acc[fm][fn], ah[fm], bhf[fn]);
            #pragma unroll
            for (int fm = 0; fm < 2; ++fm)
                #pragma unroll
                for (int fn = 0; fn < 2; ++fn)
                    mfma_bf16(acc[fm][fn], ah[fm], blf[fn]);
            #pragma unroll
            for (int fm = 0; fm < 2; ++fm)
                #pragma unroll
                for (int fn = 0; fn < 2; ++fn)
                    mfma_bf16(acc[fm][fn], al[fm], bhf[fn]);
        }
    }
    #pragma unroll
    for (int fm = 0; fm < 2; ++fm)
        #pragma unroll
        for (int fn = 0; fn < 2; ++fn) {
            int colb = n0 + w * 64 + fn * 32 + lr;
            int rowb = m0 + fm * 32 + 4 * lk;
            #pragma unroll
            for (int r = 0; r < 16; ++r) {
                int row = rowb + (r & 3) + 8 * (r >> 2);
                C[(size_t)row * HW_ + colb] = acc[fm][fn][r];
            }
        }
}

// ---------------------------------------------------------------------------
// Final: ACL scatter (9 taps of ET), mask blend, 1x1 conv + bias + ELU.
// 64-thread blocks (1 wave) x 256 blocks: spreads epilogue across all CUs.
// ---------------------------------------------------------------------------
__global__ __launch_bounds__(64) void final_kernel(const float* __restrict__ ET,
                                                   const float* __restrict__ bg_in,
                                                   const float* __restrict__ mask,
                                                   const float* __restrict__ fw,
                                                   const float* __restrict__ fb,
                                                   float* __restrict__ out) {
    __shared__ float fwT[128 * 64];               // fwT[c2][c] = fw[c*128 + c2]
    #pragma unroll 8
    for (int lin = threadIdx.x; lin < 8192; lin += 64) {
        int c = lin >> 7, c2 = lin & 127;
        fwT[(c2 << 6) + c] = fw[lin];
    }
    __syncthreads();

    int t = blockIdx.x * 64 + threadIdx.x;        // b*4096 + p
    int b = t >> 12, p = t & 4095;
    int y = p >> 6, x = p & 63;
    const float* bgp = bg_in + ((size_t)(b * C_) << 12) + p;
    const float* Eb  = ET + (size_t)b * D_ * HW_;
    float m = mask[t];

    float acc[64];
    #pragma unroll
    for (int c = 0; c < 64; ++c) acc[c] = fb[c];

    for (int c2 = 0; c2 < 64; ++c2) {
        float bgv = bgp[(size_t)c2 << 12];
        float a = 0.f;
        if (m == 0.f) {
            #pragma unroll
            for (int kk = 0; kk < 9; ++kk) {
                int i = kk / 3, j = kk - (kk / 3) * 3;
                int hh = y + 1 - i, ww2 = x + 1 - j;
                if ((unsigned)hh < 64u && (unsigned)ww2 < 64u)
                    a += Eb[(size_t)(c2 * 9 + kk) * HW_ + (hh << 6) + ww2];
            }
            a *= (1.f / 9.f);
        }
        float aclv = (m != 0.f) ? bgv : a;
        const float* f1 = &fwT[c2 << 6];
        const float* f2 = &fwT[(64 + c2) << 6];
        #pragma unroll
        for (int c4 = 0; c4 < 16; ++c4) {
            float4 fa  = *(const float4*)&f1[c4 << 2];
            float4 fb4 = *(const float4*)&f2[c4 << 2];
            acc[(c4 << 2) + 0] += fa.x * bgv + fb4.x * aclv;
            acc[(c4 << 2) + 1] += fa.y * bgv + fb4.y * aclv;
            acc[(c4 << 2) + 2] += fa.z * bgv + fb4.z * aclv;
            acc[(c4 << 2) + 3] += fa.w * bgv + fb4.w * aclv;
        }
    }
    float* op = out + ((size_t)(b * C_) << 12) + p;
    #pragma unroll
    for (int c = 0; c < 64; ++c) {
        float v = acc[c];
        op[(size_t)c << 12] = v > 0.f ? v : expm1f(v);
    }
}

extern "C" void kernel_launch(void* const* d_in, const int* in_sizes, int n_in,
                              void* d_out, int out_size, void* d_ws, size_t ws_size,
                              hipStream_t stream) {
    const float* bg_in  = (const float*)d_in[0];
    const float* fg_in  = (const float*)d_in[1];
    const float* mask   = (const float*)d_in[2];
    const float* fuse_w = (const float*)d_in[3];
    const float* fuse_b = (const float*)d_in[4];
    float* out = (float*)d_out;

    char* base = (char*)d_ws;
    u16* WWh  = (u16*)base;  base += (size_t)B_ * HW_ * D_ * 2;    // 18,874,368
    u16* WWl  = (u16*)base;  base += (size_t)B_ * HW_ * D_ * 2;
    u16* UBh  = (u16*)base;  base += (size_t)B_ * D_ * LP_ * 2;    //  4,718,592
    u16* UBl  = (u16*)base;  base += (size_t)B_ * D_ * LP_ * 2;
    u16* UBTh = (u16*)base;  base += (size_t)B_ * LP_ * D_ * 2;
    u16* UBTl = (u16*)base;  base += (size_t)B_ * LP_ * D_ * 2;
    float* CS  = (float*)base;  base += (size_t)B_ * HW_ * LP_ * 4; // 67,108,864 (CS then CA hi/lo in place)
    float* K1D = (float*)base;  base += (size_t)B_ * LP_ * 4;
    float* P   = (float*)base;  base += (size_t)B_ * HW_ * 4;
    float* ET  = (float*)WWh;   // alias: WW dead after GEMM1; 37,748,736 B fits exactly

    hipMemsetAsync(K1D, 0, (size_t)B_ * LP_ * sizeof(float), stream);
    fill_ub_kernel <<<(B_ * D_ * LP_) / 256, 256, 0, stream>>>(bg_in, mask, UBh, UBl);
    fill_ubT_kernel<<<(B_ * LP_ * D_) / 256, 256, 0, stream>>>(bg_in, mask, UBTh, UBTl);
    k1d_kernel<<<dim3((B_ * LP_) / 256, 4), 256, 0, stream>>>(UBh, UBl, K1D);
    fill_ww_kernel<<<(B_ * HW_ * D_) / 256, 256, 0, stream>>>(fg_in, WWh, WWl);
    pixsq_kernel<<<(B_ * HW_) / 256, 256, 0, stream>>>(fg_in, P);
    gemm1_kernel<<<dim3(LP_ / 128, HW_ / 128, B_), 256, 0, stream>>>(WWh, WWl, UBTh, UBTl, CS);
    stats_softmax_kernel<<<B_ * HW_, 256, 0, stream>>>(CS, K1D, P);
    gemm2_kernel<<<dim3(HW_ / 256, D_ / 64, B_), 256, 0, stream>>>(UBh, UBl, CS, ET);
    final_kernel<<<(B_ * HW_) / 64, 64, 0, stream>>>(ET, bg_in, mask, fuse_w, fuse_b, out);
}

// Round 7
// 633.156 us; speedup vs baseline: 1.0544x; 1.0544x over previous
//
#include <hip/hip_runtime.h>

#define B_   4
#define C_   64
#define HW_  4096
#define D_   576      // C * 3 * 3
#define L_   961      // 31 * 31 keys
#define LP_  1024     // padded L (zero-filled)
#define LAMDA_ 10.0f
#define EPS_   1e-6f

typedef short short8 __attribute__((ext_vector_type(8)));
typedef float f32x16 __attribute__((ext_vector_type(16)));
typedef unsigned short u16;

// round-to-nearest-even f32 -> bf16 bits
__device__ __forceinline__ u16 f2bf(float x) {
    unsigned u = __float_as_uint(x);
    u += 0x7FFFu + ((u >> 16) & 1u);
    return (u16)(u >> 16);
}
__device__ __forceinline__ float bf2f(u16 h) {
    return __uint_as_float(((unsigned)h) << 16);
}
__device__ __forceinline__ void mfma_bf16(f32x16& d, short8 a, short8 b) {
    asm volatile("v_mfma_f32_32x32x16_bf16 %0, %1, %2, %0"
                 : "+v"(d) : "v"(a), "v"(b));
}

// Direct global->LDS 16B load. LDS dest must be wave-uniform base + lane*16
// (our staging slot order satisfies this by construction).
__device__ __forceinline__ void gl16(const u16* g, u16* l) {
#if defined(__has_builtin) && __has_builtin(__builtin_amdgcn_global_load_lds)
    __builtin_amdgcn_global_load_lds(
        (const __attribute__((address_space(1))) unsigned int*)g,
        (__attribute__((address_space(3))) unsigned int*)l, 16, 0, 0);
#else
    *(uint4*)l = *(const uint4*)g;
#endif
}

// ---------------------------------------------------------------------------
// UB[b][d][l] (d-major) hi/lo: ub = bg_in*mask unfolded (k=3, s=2, pad=0)
// ---------------------------------------------------------------------------
__global__ __launch_bounds__(256) void fill_ub_kernel(const float* __restrict__ bg_in,
                                                      const float* __restrict__ mask,
                                                      u16* __restrict__ UBh,
                                                      u16* __restrict__ UBl) {
    int idx = blockIdx.x * 256 + threadIdx.x;     // b*D_*LP_ + d*LP_ + l
    int b   = idx / (D_ * LP_);
    int rem = idx - b * (D_ * LP_);
    int d   = rem >> 10;
    int l   = idx & (LP_ - 1);
    float v = 0.f;
    if (l < L_) {
        int ly = l / 31, lx = l - ly * 31;
        int c  = d / 9,  kk = d - c * 9;
        int i  = kk / 3, j  = kk - i * 3;
        int pix = ((2 * ly + i) << 6) + 2 * lx + j;
        v = bg_in[((b * C_ + c) << 12) + pix] * mask[(b << 12) + pix];
    }
    u16 h = f2bf(v);
    UBh[idx] = h;
    UBl[idx] = f2bf(v - bf2f(h));
}

// UBT[b][l][d] (l-major) hi/lo — same values, transposed layout for GEMM1 B.
__global__ __launch_bounds__(256) void fill_ubT_kernel(const float* __restrict__ bg_in,
                                                       const float* __restrict__ mask,
                                                       u16* __restrict__ UBTh,
                                                       u16* __restrict__ UBTl) {
    int idx = blockIdx.x * 256 + threadIdx.x;     // (b*LP_ + l)*D_ + d
    int d   = idx % D_;
    int tmp = idx / D_;
    int l   = tmp & (LP_ - 1);
    int b   = tmp >> 10;
    float v = 0.f;
    if (l < L_) {
        int ly = l / 31, lx = l - ly * 31;
        int c  = d / 9,  kk = d - c * 9;
        int i  = kk / 3, j  = kk - i * 3;
        int pix = ((2 * ly + i) << 6) + 2 * lx + j;
        v = bg_in[((b * C_ + c) << 12) + pix] * mask[(b << 12) + pix];
    }
    u16 h = f2bf(v);
    UBTh[idx] = h;
    UBTl[idx] = f2bf(v - bf2f(h));
}

// K1D[b][l] += partial sum over 144 d's of (hi+lo)^2
__global__ __launch_bounds__(256) void k1d_kernel(const u16* __restrict__ UBh,
                                                  const u16* __restrict__ UBl,
                                                  float* __restrict__ K1D) {
    int t = blockIdx.x * 256 + threadIdx.x;       // b*1024 + l
    int b = t >> 10;
    int l = t & 1023;
    size_t base = (size_t)b * (D_ * LP_) + (size_t)(blockIdx.y * 144) * LP_ + l;
    float s = 0.f;
    #pragma unroll 8
    for (int d = 0; d < 144; ++d) {
        float v = bf2f(UBh[base + (size_t)d * LP_]) + bf2f(UBl[base + (size_t)d * LP_]);
        s += v * v;
    }
    atomicAdd(&K1D[t], s);
}

// WW[b][p][d] hi/lo = fg unfolded (k=3, s=1, pad=1) — query patches
__global__ __launch_bounds__(256) void fill_ww_kernel(const float* __restrict__ fg,
                                                      u16* __restrict__ WWh,
                                                      u16* __restrict__ WWl) {
    int idx = blockIdx.x * 256 + threadIdx.x;     // (b*HW + p)*D + d
    int d   = idx % D_;
    int tmp = idx / D_;
    int p   = tmp & 4095;
    int b   = tmp >> 12;
    int c   = d / 9,  kk = d - c * 9;
    int i   = kk / 3, j  = kk - i * 3;
    int y   = (p >> 6) + i - 1, x = (p & 63) + j - 1;
    float v = 0.f;
    if ((unsigned)y < 64u && (unsigned)x < 64u)
        v = fg[((b * C_ + c) << 12) + (y << 6) + x];
    u16 h = f2bf(v);
    WWh[idx] = h;
    WWl[idx] = f2bf(v - bf2f(h));
}

// P[b][p] = sum_c fg^2 (exact f32)
__global__ __launch_bounds__(256) void pixsq_kernel(const float* __restrict__ fg,
                                                    float* __restrict__ P) {
    int t = blockIdx.x * 256 + threadIdx.x;
    int b = t >> 12, p = t & 4095;
    const float* base = fg + ((size_t)(b * C_) << 12) + p;
    float s = 0.f;
    #pragma unroll 8
    for (int c = 0; c < C_; ++c) { float v = base[c << 12]; s += v * v; }
    P[t] = s;
}

// ---------------------------------------------------------------------------
// GEMM1: CS[b][q][l] = sum_d WW[q][d]*UB[d][l], bf16x3 MFMA 32x32x16.
// Block 128x128, 4 waves (2x2). Double-buffered global_load_lds staging.
// ---------------------------------------------------------------------------
__device__ __forceinline__ void g1_stage(const u16* Ahg, const u16* Alg,
                                         const u16* Bhg, const u16* Blg,
                                         u16* sAh, u16* sAl, u16* sBh, u16* sBl,
                                         int t, int m0, int n0, int k0) {
    #pragma unroll
    for (int i = 0; i < 2; ++i) {                 // 512 16B slots per matrix
        int lin = i * 256 + t;
        int q = lin >> 7, r = lin & 127;
        size_t ga = (size_t)(m0 + r) * D_ + k0 + q * 8;
        size_t gb = (size_t)(n0 + r) * D_ + k0 + q * 8;
        gl16(Ahg + ga, sAh + lin * 8);
        gl16(Alg + ga, sAl + lin * 8);
        gl16(Bhg + gb, sBh + lin * 8);
        gl16(Blg + gb, sBl + lin * 8);
    }
}

__global__ __launch_bounds__(256) void gemm1_kernel(
    const u16* __restrict__ WWh, const u16* __restrict__ WWl,
    const u16* __restrict__ UBTh, const u16* __restrict__ UBTl,
    float* __restrict__ CS)
{
    int b = blockIdx.z;
    const u16* Ahg = WWh  + (size_t)b * HW_ * D_;
    const u16* Alg = WWl  + (size_t)b * HW_ * D_;
    const u16* Bhg = UBTh + (size_t)b * LP_ * D_;
    const u16* Blg = UBTl + (size_t)b * LP_ * D_;
    float* C = CS + (size_t)b * HW_ * LP_;
    int n0 = blockIdx.x << 7, m0 = blockIdx.y << 7;

    __shared__ __align__(16) u16 Ah[2][4096], Al[2][4096], Bh[2][4096], Bl[2][4096];

    int t = threadIdx.x;
    int lane = t & 63;
    int w = t >> 6, wm = w >> 1, wn = w & 1;
    int lr = lane & 31, lk = lane >> 5;

    f32x16 acc[2][2];
    #pragma unroll
    for (int i = 0; i < 2; ++i)
        #pragma unroll
        for (int j = 0; j < 2; ++j)
            #pragma unroll
            for (int r = 0; r < 16; ++r) acc[i][j][r] = 0.f;

    g1_stage(Ahg, Alg, Bhg, Blg, Ah[0], Al[0], Bh[0], Bl[0], t, m0, n0, 0);
    __syncthreads();                               // drains vmcnt(0): buf0 ready
    int cur = 0;
    for (int it = 0; it < 18; ++it) {              // D_/32 = 18
        if (it < 17)                               // prefetch next tile into other buf
            g1_stage(Ahg, Alg, Bhg, Blg,
                     Ah[cur ^ 1], Al[cur ^ 1], Bh[cur ^ 1], Bl[cur ^ 1],
                     t, m0, n0, (it + 1) * 32);
        const u16* sAh = Ah[cur]; const u16* sAl = Al[cur];
        const u16* sBh = Bh[cur]; const u16* sBl = Bl[cur];
        #pragma unroll
        for (int kh = 0; kh < 2; ++kh) {
            int qq = kh * 2 + lk;
            short8 ah[2], al[2], bhf[2], blf[2];
            #pragma unroll
            for (int f = 0; f < 2; ++f) {
                int ra = (qq * 128 + wm * 64 + f * 32 + lr) * 8;
                int rb = (qq * 128 + wn * 64 + f * 32 + lr) * 8;
                ah[f]  = *(const short8*)&sAh[ra];
                al[f]  = *(const short8*)&sAl[ra];
                bhf[f] = *(const short8*)&sBh[rb];
                blf[f] = *(const short8*)&sBl[rb];
            }
            #pragma unroll
            for (int fm = 0; fm < 2; ++fm)
                #pragma unroll
                for (int fn = 0; fn < 2; ++fn)
                    mfma_bf16(acc[fm][fn], ah[fm], bhf[fn]);
            #pragma unroll
            for (int fm = 0; fm < 2; ++fm)
                #pragma unroll
                for (int fn = 0; fn < 2; ++fn)
                    mfma_bf16(acc[fm][fn], ah[fm], blf[fn]);
            #pragma unroll
            for (int fm = 0; fm < 2; ++fm)
                #pragma unroll
                for (int fn = 0; fn < 2; ++fn)
                    mfma_bf16(acc[fm][fn], al[fm], bhf[fn]);
        }
        __syncthreads();                           // LDS reads done + next buf loaded
        cur ^= 1;
    }
    #pragma unroll
    for (int fm = 0; fm < 2; ++fm)
        #pragma unroll
        for (int fn = 0; fn < 2; ++fn) {
            int colb = n0 + wn * 64 + fn * 32 + lr;
            int rowb = m0 + wm * 64 + fm * 32 + 4 * lk;
            #pragma unroll
            for (int r = 0; r < 16; ++r) {
                int row = rowb + (r & 3) + 8 * (r >> 2);
                C[(size_t)row * LP_ + colb] = acc[fm][fn][r];
            }
        }
}

// ---------------------------------------------------------------------------
// Row stats + tanh + softmax. Reads f32 CS row, writes bf16 hi/lo IN PLACE.
// ---------------------------------------------------------------------------
__device__ __forceinline__ float block_reduce_sum(float v, float* sred) {
    #pragma unroll
    for (int m = 32; m > 0; m >>= 1) v += __shfl_xor(v, m, 64);
    __syncthreads();
    if ((threadIdx.x & 63) == 0) sred[threadIdx.x >> 6] = v;
    __syncthreads();
    return sred[0] + sred[1] + sred[2] + sred[3];
}

__global__ __launch_bounds__(256) void stats_softmax_kernel(float* __restrict__ CA,
                                                            const float* __restrict__ K1D,
                                                            const float* __restrict__ P) {
    __shared__ float sred[4];
    int row = blockIdx.x;                         // b*4096 + q
    int b = row >> 12, q = row & 4095;
    int h = q >> 6, wx = q & 63;
    float wwd = 0.f;
    #pragma unroll
    for (int i = 0; i < 3; ++i)
        #pragma unroll
        for (int j = 0; j < 3; ++j) {
            int y = h + i - 1, x = wx + j - 1;
            if ((unsigned)y < 64u && (unsigned)x < 64u)
                wwd += P[(b << 12) + (y << 6) + x];
        }
    float* cs = CA + (size_t)row * LP_;
    u16* ch = (u16*)cs;                           // in-place overlay
    const float* k1 = K1D + (b << 10);
    int t = threadIdx.x;
    float xv[4];
    float lsum = 0.f;
    #pragma unroll
    for (int i = 0; i < 4; ++i) {
        int l = t + (i << 8);
        float ds = 0.f;
        if (l < L_) ds = k1[l] + wwd - 2.f * cs[l];
        xv[i] = ds;
        lsum += ds;
    }
    float mean = block_reduce_sum(lsum, sred) * (1.f / 961.f);
    float lvar = 0.f;
    #pragma unroll
    for (int i = 0; i < 4; ++i) {
        int l = t + (i << 8);
        if (l < L_) { float dd = xv[i] - mean; lvar += dd * dd; }
    }
    float var = block_reduce_sum(lvar, sred) * (1.f / 961.f);
    float inv = 1.f / (sqrtf(var) + EPS_);
    float ev[4];
    float lsume = 0.f;
    #pragma unroll
    for (int i = 0; i < 4; ++i) {
        int l = t + (i << 8);
        float e = 0.f;
        if (l < L_) e = expf(-LAMDA_ * tanhf((xv[i] - mean) * inv));
        ev[i] = e;
        lsume += e;
    }
    float rs = 1.f / block_reduce_sum(lsume, sred);
    #pragma unroll
    for (int i = 0; i < 4; ++i) {                 // all reads done (barriers above)
        int l2 = t + (i << 8);
        float v = ev[i] * rs;                     // pad -> exact 0
        u16 hi = f2bf(v);
        ch[l2]        = hi;
        ch[1024 + l2] = f2bf(v - bf2f(hi));
    }
}

// ---------------------------------------------------------------------------
// GEMM2: ET[b][d][q] = sum_l UB[d][l]*CA[q][l], bf16x3 MFMA (NT).
// Block 64x256, 4 waves (1x4). Double-buffered global_load_lds staging.
// ---------------------------------------------------------------------------
__device__ __forceinline__ void g2_stage(const u16* Ahg, const u16* Alg,
                                         const u16* CAB,
                                         u16* sAh, u16* sAl, u16* sBh, u16* sBl,
                                         int t, int m0, int n0, int k0) {
    {                                             // A: 256 slots
        int q = t >> 6, r = t & 63;
        size_t ga = (size_t)(m0 + r) * LP_ + k0 + q * 8;
        gl16(Ahg + ga, sAh + t * 8);
        gl16(Alg + ga, sAl + t * 8);
    }
    #pragma unroll
    for (int i = 0; i < 4; ++i) {                 // B: 1024 slots
        int lin = i * 256 + t;
        int q = lin >> 8, r = lin & 255;
        size_t gb = (size_t)(n0 + r) * 2048 + k0 + q * 8;
        gl16(CAB + gb,        sBh + lin * 8);
        gl16(CAB + gb + 1024, sBl + lin * 8);
    }
}

__global__ __launch_bounds__(256) void gemm2_kernel(
    const u16* __restrict__ UBh, const u16* __restrict__ UBl,
    const float* __restrict__ CAbase, float* __restrict__ ET)
{
    int b = blockIdx.z;
    const u16* Ahg = UBh + (size_t)b * D_ * LP_;
    const u16* Alg = UBl + (size_t)b * D_ * LP_;
    const u16* CAB = (const u16*)(CAbase + (size_t)b * HW_ * LP_);   // rows: 2048 u16
    float* C = ET + (size_t)b * D_ * HW_;
    int n0 = blockIdx.x << 8, m0 = blockIdx.y << 6;

    __shared__ __align__(16) u16 Ah[2][2048], Al[2][2048], Bh[2][8192], Bl[2][8192];

    int t = threadIdx.x;
    int lane = t & 63;
    int w = t >> 6;
    int lr = lane & 31, lk = lane >> 5;

    f32x16 acc[2][2];
    #pragma unroll
    for (int i = 0; i < 2; ++i)
        #pragma unroll
        for (int j = 0; j < 2; ++j)
            #pragma unroll
            for (int r = 0; r < 16; ++r) acc[i][j][r] = 0.f;

    g2_stage(Ahg, Alg, CAB, Ah[0], Al[0], Bh[0], Bl[0], t, m0, n0, 0);
    __syncthreads();
    int cur = 0;
    for (int it = 0; it < 32; ++it) {             // LP_/32
        if (it < 31)
            g2_stage(Ahg, Alg, CAB,
                     Ah[cur ^ 1], Al[cur ^ 1], Bh[cur ^ 1], Bl[cur ^ 1],
                     t, m0, n0, (it + 1) * 32);
        const u16* sAh = Ah[cur]; const u16* sAl = Al[cur];
        const u16* sBh = Bh[cur]; const u16* sBl = Bl[cur];
        #pragma unroll
        for (int kh = 0; kh < 2; ++kh) {
            int qq = kh * 2 + lk;
            short8 ah[2], al[2], bhf[2], blf[2];
            #pragma unroll
            for (int f = 0; f < 2; ++f) {
                int ra = (qq * 64 + f * 32 + lr) * 8;
                int rb = (qq * 256 + w * 64 + f * 32 + lr) * 8;
                ah[f]  = *(const short8*)&sAh[ra];
                al[f]  = *(const short8*)&sAl[ra];
                bhf[f] = *(const short8*)&sBh[rb];
                blf[f] = *(const short8*)&sBl[rb];
            }
            #pragma unroll
            for (int fm = 0; fm < 2; ++fm)
                #pragma unroll
                for (int fn = 0; fn < 2; ++fn)
                    mfma_bf16(acc[fm][fn], ah[fm], bhf[fn]);
            #pragma unroll
            for (int fm = 0; fm < 2; ++fm)
                #pragma unroll
                for (int fn = 0; fn < 2; ++fn)
                    mfma_bf16(acc[fm][fn], ah[fm], blf[fn]);
            #pragma unroll
            for (int fm = 0; fm < 2; ++fm)
                #pragma unroll
                for (int fn = 0; fn < 2; ++fn)
                    mfma_bf16(acc[fm][fn], al[fm], bhf[fn]);
        }
        __syncthreads();
        cur ^= 1;
    }
    #pragma unroll
    for (int fm = 0; fm < 2; ++fm)
        #pragma unroll
        for (int fn = 0; fn < 2; ++fn) {
            int colb = n0 + w * 64 + fn * 32 + lr;
            int rowb = m0 + fm * 32 + 4 * lk;
            #pragma unroll
            for (int r = 0; r < 16; ++r) {
                int row = rowb + (r & 3) + 8 * (r >> 2);
                C[(size_t)row * HW_ + colb] = acc[fm][fn][r];
            }
        }
}

// ---------------------------------------------------------------------------
// Final: ACL scatter (9 taps of ET), mask blend, 1x1 conv + bias + ELU.
// 256 blocks x 256 threads; thread = (channel-quarter, pixel). 4 waves/CU.
// Gathers are duplicated across the 4 quarters of a pixel but L1-resident.
// ---------------------------------------------------------------------------
__global__ __launch_bounds__(256) void final_kernel(const float* __restrict__ ET,
                                                    const float* __restrict__ bg_in,
                                                    const float* __restrict__ mask,
                                                    const float* __restrict__ fw,
                                                    const float* __restrict__ fb,
                                                    float* __restrict__ out) {
    __shared__ float fwT[128 * 64];               // fwT[c2][c] = fw[c*128 + c2]
    #pragma unroll
    for (int i = 0; i < 32; ++i) {
        int lin = i * 256 + threadIdx.x;
        int c = lin >> 7, c2 = lin & 127;
        fwT[(c2 << 6) + c] = fw[lin];
    }
    __syncthreads();

    int qc = threadIdx.x >> 6;                    // channel quarter 0..3 (wave-uniform)
    int px = threadIdx.x & 63;
    int gp = blockIdx.x * 64 + px;                // b*4096 + p
    int b = gp >> 12, p = gp & 4095;
    int y = p >> 6, x = p & 63;
    const float* bgp = bg_in + ((size_t)(b * C_) << 12) + p;
    const float* Eb  = ET + (size_t)b * D_ * HW_;
    float m = mask[gp];
    int c0 = qc << 4;

    float acc[16];
    #pragma unroll
    for (int c = 0; c < 16; ++c) acc[c] = fb[c0 + c];

    for (int c2 = 0; c2 < 64; ++c2) {
        float bgv = bgp[(size_t)c2 << 12];
        float a = 0.f;
        if (m == 0.f) {
            #pragma unroll
            for (int kk = 0; kk < 9; ++kk) {
                int i = kk / 3, j = kk - (kk / 3) * 3;
                int hh = y + 1 - i, ww2 = x + 1 - j;
                if ((unsigned)hh < 64u && (unsigned)ww2 < 64u)
                    a += Eb[(size_t)(c2 * 9 + kk) * HW_ + (hh << 6) + ww2];
            }
            a *= (1.f / 9.f);
        }
        float aclv = (m != 0.f) ? bgv : a;
        const float* f1 = &fwT[(c2 << 6) + c0];        // broadcast reads (free)
        const float* f2 = &fwT[((64 + c2) << 6) + c0];
        #pragma unroll
        for (int c4 = 0; c4 < 4; ++c4) {
            float4 fa  = *(const float4*)&f1[c4 << 2];
            float4 fb4 = *(const float4*)&f2[c4 << 2];
            acc[(c4 << 2) + 0] += fa.x * bgv + fb4.x * aclv;
            acc[(c4 << 2) + 1] += fa.y * bgv + fb4.y * aclv;
            acc[(c4 << 2) + 2] += fa.z * bgv + fb4.z * aclv;
            acc[(c4 << 2) + 3] += fa.w * bgv + fb4.w * aclv;
        }
    }
    float* op = out + ((size_t)(b * C_) << 12) + p;
    #pragma unroll
    for (int c = 0; c < 16; ++c) {
        float v = acc[c];
        op[(size_t)(c0 + c) << 12] = v > 0.f ? v : expm1f(v);
    }
}

extern "C" void kernel_launch(void* const* d_in, const int* in_sizes, int n_in,
                              void* d_out, int out_size, void* d_ws, size_t ws_size,
                              hipStream_t stream) {
    const float* bg_in  = (const float*)d_in[0];
    const float* fg_in  = (const float*)d_in[1];
    const float* mask   = (const float*)d_in[2];
    const float* fuse_w = (const float*)d_in[3];
    const float* fuse_b = (const float*)d_in[4];
    float* out = (float*)d_out;

    char* base = (char*)d_ws;
    u16* WWh  = (u16*)base;  base += (size_t)B_ * HW_ * D_ * 2;
    u16* WWl  = (u16*)base;  base += (size_t)B_ * HW_ * D_ * 2;
    u16* UBh  = (u16*)base;  base += (size_t)B_ * D_ * LP_ * 2;
    u16* UBl  = (u16*)base;  base += (size_t)B_ * D_ * LP_ * 2;
    u16* UBTh = (u16*)base;  base += (size_t)B_ * LP_ * D_ * 2;
    u16* UBTl = (u16*)base;  base += (size_t)B_ * LP_ * D_ * 2;
    float* CS  = (float*)base;  base += (size_t)B_ * HW_ * LP_ * 4;
    float* K1D = (float*)base;  base += (size_t)B_ * LP_ * 4;
    float* P   = (float*)base;  base += (size_t)B_ * HW_ * 4;
    float* ET  = (float*)WWh;   // alias: WW dead after GEMM1

    hipMemsetAsync(K1D, 0, (size_t)B_ * LP_ * sizeof(float), stream);
    fill_ub_kernel <<<(B_ * D_ * LP_) / 256, 256, 0, stream>>>(bg_in, mask, UBh, UBl);
    fill_ubT_kernel<<<(B_ * LP_ * D_) / 256, 256, 0, stream>>>(bg_in, mask, UBTh, UBTl);
    k1d_kernel<<<dim3((B_ * LP_) / 256, 4), 256, 0, stream>>>(UBh, UBl, K1D);
    fill_ww_kernel<<<(B_ * HW_ * D_) / 256, 256, 0, stream>>>(fg_in, WWh, WWl);
    pixsq_kernel<<<(B_ * HW_) / 256, 256, 0, stream>>>(fg_in, P);
    gemm1_kernel<<<dim3(LP_ / 128, HW_ / 128, B_), 256, 0, stream>>>(WWh, WWl, UBTh, UBTl, CS);
    stats_softmax_kernel<<<B_ * HW_, 256, 0, stream>>>(CS, K1D, P);
    gemm2_kernel<<<dim3(HW_ / 256, D_ / 64, B_), 256, 0, stream>>>(UBh, UBl, CS, ET);
    final_kernel<<<(B_ * HW_) / 64, 256, 0, stream>>>(ET, bg_in, mask, fuse_w, fuse_b, out);
}

// Round 8
// 629.443 us; speedup vs baseline: 1.0606x; 1.0059x over previous
//
#include <hip/hip_runtime.h>

#define B_   4
#define C_   64
#define HW_  4096
#define D_   576      // C * 3 * 3
#define L_   961      // 31 * 31 keys
#define LP_  1024     // padded L (zero-filled)
#define LAMDA_ 10.0f
#define EPS_   1e-6f

typedef short short8 __attribute__((ext_vector_type(8)));
typedef float f32x16 __attribute__((ext_vector_type(16)));
typedef unsigned short u16;

// round-to-nearest-even f32 -> bf16 bits
__device__ __forceinline__ u16 f2bf(float x) {
    unsigned u = __float_as_uint(x);
    u += 0x7FFFu + ((u >> 16) & 1u);
    return (u16)(u >> 16);
}
__device__ __forceinline__ float bf2f(u16 h) {
    return __uint_as_float(((unsigned)h) << 16);
}
__device__ __forceinline__ void mfma_bf16(f32x16& d, short8 a, short8 b) {
    asm volatile("v_mfma_f32_32x32x16_bf16 %0, %1, %2, %0"
                 : "+v"(d) : "v"(a), "v"(b));
}

// Direct global->LDS 16B load. LDS dest must be wave-uniform base + lane*16
// (our staging slot order satisfies this by construction).
__device__ __forceinline__ void gl16(const u16* g, u16* l) {
#if defined(__has_builtin) && __has_builtin(__builtin_amdgcn_global_load_lds)
    __builtin_amdgcn_global_load_lds(
        (const __attribute__((address_space(1))) unsigned int*)g,
        (__attribute__((address_space(3))) unsigned int*)l, 16, 0, 0);
#else
    *(uint4*)l = *(const uint4*)g;
#endif
}

// ---------------------------------------------------------------------------
// UB[b][d][l] (d-major) hi/lo: ub = bg_in*mask unfolded (k=3, s=2, pad=0)
// ---------------------------------------------------------------------------
__global__ __launch_bounds__(256) void fill_ub_kernel(const float* __restrict__ bg_in,
                                                      const float* __restrict__ mask,
                                                      u16* __restrict__ UBh,
                                                      u16* __restrict__ UBl) {
    int idx = blockIdx.x * 256 + threadIdx.x;     // b*D_*LP_ + d*LP_ + l
    int b   = idx / (D_ * LP_);
    int rem = idx - b * (D_ * LP_);
    int d   = rem >> 10;
    int l   = idx & (LP_ - 1);
    float v = 0.f;
    if (l < L_) {
        int ly = l / 31, lx = l - ly * 31;
        int c  = d / 9,  kk = d - c * 9;
        int i  = kk / 3, j  = kk - i * 3;
        int pix = ((2 * ly + i) << 6) + 2 * lx + j;
        v = bg_in[((b * C_ + c) << 12) + pix] * mask[(b << 12) + pix];
    }
    u16 h = f2bf(v);
    UBh[idx] = h;
    UBl[idx] = f2bf(v - bf2f(h));
}

// UBT[b][l][d] (l-major) hi/lo — same values, transposed layout for GEMM1 B.
__global__ __launch_bounds__(256) void fill_ubT_kernel(const float* __restrict__ bg_in,
                                                       const float* __restrict__ mask,
                                                       u16* __restrict__ UBTh,
                                                       u16* __restrict__ UBTl) {
    int idx = blockIdx.x * 256 + threadIdx.x;     // (b*LP_ + l)*D_ + d
    int d   = idx % D_;
    int tmp = idx / D_;
    int l   = tmp & (LP_ - 1);
    int b   = tmp >> 10;
    float v = 0.f;
    if (l < L_) {
        int ly = l / 31, lx = l - ly * 31;
        int c  = d / 9,  kk = d - c * 9;
        int i  = kk / 3, j  = kk - i * 3;
        int pix = ((2 * ly + i) << 6) + 2 * lx + j;
        v = bg_in[((b * C_ + c) << 12) + pix] * mask[(b << 12) + pix];
    }
    u16 h = f2bf(v);
    UBTh[idx] = h;
    UBTl[idx] = f2bf(v - bf2f(h));
}

// K1D[b][l] += partial sum over 144 d's of (hi+lo)^2
__global__ __launch_bounds__(256) void k1d_kernel(const u16* __restrict__ UBh,
                                                  const u16* __restrict__ UBl,
                                                  float* __restrict__ K1D) {
    int t = blockIdx.x * 256 + threadIdx.x;       // b*1024 + l
    int b = t >> 10;
    int l = t & 1023;
    size_t base = (size_t)b * (D_ * LP_) + (size_t)(blockIdx.y * 144) * LP_ + l;
    float s = 0.f;
    #pragma unroll 8
    for (int d = 0; d < 144; ++d) {
        float v = bf2f(UBh[base + (size_t)d * LP_]) + bf2f(UBl[base + (size_t)d * LP_]);
        s += v * v;
    }
    atomicAdd(&K1D[t], s);
}

// WW[b][p][d] hi/lo = fg unfolded (k=3, s=1, pad=1) — query patches
__global__ __launch_bounds__(256) void fill_ww_kernel(const float* __restrict__ fg,
                                                      u16* __restrict__ WWh,
                                                      u16* __restrict__ WWl) {
    int idx = blockIdx.x * 256 + threadIdx.x;     // (b*HW + p)*D + d
    int d   = idx % D_;
    int tmp = idx / D_;
    int p   = tmp & 4095;
    int b   = tmp >> 12;
    int c   = d / 9,  kk = d - c * 9;
    int i   = kk / 3, j  = kk - i * 3;
    int y   = (p >> 6) + i - 1, x = (p & 63) + j - 1;
    float v = 0.f;
    if ((unsigned)y < 64u && (unsigned)x < 64u)
        v = fg[((b * C_ + c) << 12) + (y << 6) + x];
    u16 h = f2bf(v);
    WWh[idx] = h;
    WWl[idx] = f2bf(v - bf2f(h));
}

// P[b][p] = sum_c fg^2 (exact f32)
__global__ __launch_bounds__(256) void pixsq_kernel(const float* __restrict__ fg,
                                                    float* __restrict__ P) {
    int t = blockIdx.x * 256 + threadIdx.x;
    int b = t >> 12, p = t & 4095;
    const float* base = fg + ((size_t)(b * C_) << 12) + p;
    float s = 0.f;
    #pragma unroll 8
    for (int c = 0; c < C_; ++c) { float v = base[c << 12]; s += v * v; }
    P[t] = s;
}

// ---------------------------------------------------------------------------
// GEMM1: CS[b][q][l] = sum_d WW[q][d]*UB[d][l], bf16x3 MFMA 32x32x16.
// Block 128x128, 4 waves (2x2). 2-deep pipeline, counted vmcnt (never 0 in
// steady state) — loads for tile k+1 stay in flight across tile k's compute.
// ---------------------------------------------------------------------------
__device__ __forceinline__ void g1_stage(const u16* Ahg, const u16* Alg,
                                         const u16* Bhg, const u16* Blg,
                                         u16* sAh, u16* sAl, u16* sBh, u16* sBl,
                                         int t, int m0, int n0, int k0) {
    #pragma unroll
    for (int i = 0; i < 2; ++i) {                 // 8 VMEM instrs per thread total
        int lin = i * 256 + t;
        int q = lin >> 7, r = lin & 127;
        size_t ga = (size_t)(m0 + r) * D_ + k0 + q * 8;
        size_t gb = (size_t)(n0 + r) * D_ + k0 + q * 8;
        gl16(Ahg + ga, sAh + lin * 8);
        gl16(Alg + ga, sAl + lin * 8);
        gl16(Bhg + gb, sBh + lin * 8);
        gl16(Blg + gb, sBl + lin * 8);
    }
}

__global__ __launch_bounds__(256) void gemm1_kernel(
    const u16* __restrict__ WWh, const u16* __restrict__ WWl,
    const u16* __restrict__ UBTh, const u16* __restrict__ UBTl,
    float* __restrict__ CS)
{
    int b = blockIdx.z;
    const u16* Ahg = WWh  + (size_t)b * HW_ * D_;
    const u16* Alg = WWl  + (size_t)b * HW_ * D_;
    const u16* Bhg = UBTh + (size_t)b * LP_ * D_;
    const u16* Blg = UBTl + (size_t)b * LP_ * D_;
    float* C = CS + (size_t)b * HW_ * LP_;
    int n0 = blockIdx.x << 7, m0 = blockIdx.y << 7;

    __shared__ __align__(16) u16 Ah[2][4096], Al[2][4096], Bh[2][4096], Bl[2][4096];

    int t = threadIdx.x;
    int lane = t & 63;
    int w = t >> 6, wm = w >> 1, wn = w & 1;
    int lr = lane & 31, lk = lane >> 5;

    f32x16 acc[2][2];
    #pragma unroll
    for (int i = 0; i < 2; ++i)
        #pragma unroll
        for (int j = 0; j < 2; ++j)
            #pragma unroll
            for (int r = 0; r < 16; ++r) acc[i][j][r] = 0.f;

    g1_stage(Ahg, Alg, Bhg, Blg, Ah[0], Al[0], Bh[0], Bl[0], t, m0, n0, 0);
    g1_stage(Ahg, Alg, Bhg, Blg, Ah[1], Al[1], Bh[1], Bl[1], t, m0, n0, 32);
    int cur = 0;
    for (int it = 0; it < 18; ++it) {              // D_/32 = 18
        // wait for THIS tile's 8 loads only; next tile's 8 stay in flight
        if (it < 17) asm volatile("s_waitcnt vmcnt(8)" ::: "memory");
        else         asm volatile("s_waitcnt vmcnt(0)" ::: "memory");
        __builtin_amdgcn_s_barrier();              // all waves: buf[cur] ready
        const u16* sAh = Ah[cur]; const u16* sAl = Al[cur];
        const u16* sBh = Bh[cur]; const u16* sBl = Bl[cur];
        #pragma unroll
        for (int kh = 0; kh < 2; ++kh) {
            int qq = kh * 2 + lk;
            short8 ah[2], al[2], bhf[2], blf[2];
            #pragma unroll
            for (int f = 0; f < 2; ++f) {
                int ra = (qq * 128 + wm * 64 + f * 32 + lr) * 8;
                int rb = (qq * 128 + wn * 64 + f * 32 + lr) * 8;
                ah[f]  = *(const short8*)&sAh[ra];
                al[f]  = *(const short8*)&sAl[ra];
                bhf[f] = *(const short8*)&sBh[rb];
                blf[f] = *(const short8*)&sBl[rb];
            }
            #pragma unroll
            for (int fm = 0; fm < 2; ++fm)
                #pragma unroll
                for (int fn = 0; fn < 2; ++fn)
                    mfma_bf16(acc[fm][fn], ah[fm], bhf[fn]);
            #pragma unroll
            for (int fm = 0; fm < 2; ++fm)
                #pragma unroll
                for (int fn = 0; fn < 2; ++fn)
                    mfma_bf16(acc[fm][fn], ah[fm], blf[fn]);
            #pragma unroll
            for (int fm = 0; fm < 2; ++fm)
                #pragma unroll
                for (int fn = 0; fn < 2; ++fn)
                    mfma_bf16(acc[fm][fn], al[fm], bhf[fn]);
        }
        asm volatile("s_waitcnt lgkmcnt(0)" ::: "memory");
        __builtin_amdgcn_s_barrier();              // all waves done reading buf[cur]
        if (it < 16)                               // re-stage buf[cur] with tile it+2
            g1_stage(Ahg, Alg, Bhg, Blg,
                     Ah[cur], Al[cur], Bh[cur], Bl[cur], t, m0, n0, (it + 2) * 32);
        cur ^= 1;
    }
    #pragma unroll
    for (int fm = 0; fm < 2; ++fm)
        #pragma unroll
        for (int fn = 0; fn < 2; ++fn) {
            int colb = n0 + wn * 64 + fn * 32 + lr;
            int rowb = m0 + wm * 64 + fm * 32 + 4 * lk;
            #pragma unroll
            for (int r = 0; r < 16; ++r) {
                int row = rowb + (r & 3) + 8 * (r >> 2);
                C[(size_t)row * LP_ + colb] = acc[fm][fn][r];
            }
        }
}

// ---------------------------------------------------------------------------
// Row stats + tanh + softmax. Reads f32 CS row, writes bf16 hi/lo IN PLACE.
// ---------------------------------------------------------------------------
__device__ __forceinline__ float block_reduce_sum(float v, float* sred) {
    #pragma unroll
    for (int m = 32; m > 0; m >>= 1) v += __shfl_xor(v, m, 64);
    __syncthreads();
    if ((threadIdx.x & 63) == 0) sred[threadIdx.x >> 6] = v;
    __syncthreads();
    return sred[0] + sred[1] + sred[2] + sred[3];
}

__global__ __launch_bounds__(256) void stats_softmax_kernel(float* __restrict__ CA,
                                                            const float* __restrict__ K1D,
                                                            const float* __restrict__ P) {
    __shared__ float sred[4];
    int row = blockIdx.x;                         // b*4096 + q
    int b = row >> 12, q = row & 4095;
    int h = q >> 6, wx = q & 63;
    float wwd = 0.f;
    #pragma unroll
    for (int i = 0; i < 3; ++i)
        #pragma unroll
        for (int j = 0; j < 3; ++j) {
            int y = h + i - 1, x = wx + j - 1;
            if ((unsigned)y < 64u && (unsigned)x < 64u)
                wwd += P[(b << 12) + (y << 6) + x];
        }
    float* cs = CA + (size_t)row * LP_;
    u16* ch = (u16*)cs;                           // in-place overlay
    const float* k1 = K1D + (b << 10);
    int t = threadIdx.x;
    float xv[4];
    float lsum = 0.f;
    #pragma unroll
    for (int i = 0; i < 4; ++i) {
        int l = t + (i << 8);
        float ds = 0.f;
        if (l < L_) ds = k1[l] + wwd - 2.f * cs[l];
        xv[i] = ds;
        lsum += ds;
    }
    float mean = block_reduce_sum(lsum, sred) * (1.f / 961.f);
    float lvar = 0.f;
    #pragma unroll
    for (int i = 0; i < 4; ++i) {
        int l = t + (i << 8);
        if (l < L_) { float dd = xv[i] - mean; lvar += dd * dd; }
    }
    float var = block_reduce_sum(lvar, sred) * (1.f / 961.f);
    float inv = 1.f / (sqrtf(var) + EPS_);
    float ev[4];
    float lsume = 0.f;
    #pragma unroll
    for (int i = 0; i < 4; ++i) {
        int l = t + (i << 8);
        float e = 0.f;
        if (l < L_) e = expf(-LAMDA_ * tanhf((xv[i] - mean) * inv));
        ev[i] = e;
        lsume += e;
    }
    float rs = 1.f / block_reduce_sum(lsume, sred);
    #pragma unroll
    for (int i = 0; i < 4; ++i) {                 // all reads done (barriers above)
        int l2 = t + (i << 8);
        float v = ev[i] * rs;                     // pad -> exact 0
        u16 hi = f2bf(v);
        ch[l2]        = hi;
        ch[1024 + l2] = f2bf(v - bf2f(hi));
    }
}

// ---------------------------------------------------------------------------
// GEMM2: ET[b][d][q] = sum_l UB[d][l]*CA[q][l], bf16x3 MFMA (NT).
// Block 64x256, 4 waves (1x4). 2-deep pipeline, counted vmcnt.
// ---------------------------------------------------------------------------
__device__ __forceinline__ void g2_stage(const u16* Ahg, const u16* Alg,
                                         const u16* CAB,
                                         u16* sAh, u16* sAl, u16* sBh, u16* sBl,
                                         int t, int m0, int n0, int k0) {
    {                                             // A: 2 VMEM per thread
        int q = t >> 6, r = t & 63;
        size_t ga = (size_t)(m0 + r) * LP_ + k0 + q * 8;
        gl16(Ahg + ga, sAh + t * 8);
        gl16(Alg + ga, sAl + t * 8);
    }
    #pragma unroll
    for (int i = 0; i < 4; ++i) {                 // B: 8 VMEM per thread
        int lin = i * 256 + t;
        int q = lin >> 8, r = lin & 255;
        size_t gb = (size_t)(n0 + r) * 2048 + k0 + q * 8;
        gl16(CAB + gb,        sBh + lin * 8);
        gl16(CAB + gb + 1024, sBl + lin * 8);
    }
}

__global__ __launch_bounds__(256) void gemm2_kernel(
    const u16* __restrict__ UBh, const u16* __restrict__ UBl,
    const float* __restrict__ CAbase, float* __restrict__ ET)
{
    int b = blockIdx.z;
    const u16* Ahg = UBh + (size_t)b * D_ * LP_;
    const u16* Alg = UBl + (size_t)b * D_ * LP_;
    const u16* CAB = (const u16*)(CAbase + (size_t)b * HW_ * LP_);   // rows: 2048 u16
    float* C = ET + (size_t)b * D_ * HW_;
    int n0 = blockIdx.x << 8, m0 = blockIdx.y << 6;

    __shared__ __align__(16) u16 Ah[2][2048], Al[2][2048], Bh[2][8192], Bl[2][8192];

    int t = threadIdx.x;
    int lane = t & 63;
    int w = t >> 6;
    int lr = lane & 31, lk = lane >> 5;

    f32x16 acc[2][2];
    #pragma unroll
    for (int i = 0; i < 2; ++i)
        #pragma unroll
        for (int j = 0; j < 2; ++j)
            #pragma unroll
            for (int r = 0; r < 16; ++r) acc[i][j][r] = 0.f;

    g2_stage(Ahg, Alg, CAB, Ah[0], Al[0], Bh[0], Bl[0], t, m0, n0, 0);
    g2_stage(Ahg, Alg, CAB, Ah[1], Al[1], Bh[1], Bl[1], t, m0, n0, 32);
    int cur = 0;
    for (int it = 0; it < 32; ++it) {             // LP_/32
        if (it < 31) asm volatile("s_waitcnt vmcnt(10)" ::: "memory");
        else         asm volatile("s_waitcnt vmcnt(0)"  ::: "memory");
        __builtin_amdgcn_s_barrier();             // buf[cur] ready for all waves
        const u16* sAh = Ah[cur]; const u16* sAl = Al[cur];
        const u16* sBh = Bh[cur]; const u16* sBl = Bl[cur];
        #pragma unroll
        for (int kh = 0; kh < 2; ++kh) {
            int qq = kh * 2 + lk;
            short8 ah[2], al[2], bhf[2], blf[2];
            #pragma unroll
            for (int f = 0; f < 2; ++f) {
                int ra = (qq * 64 + f * 32 + lr) * 8;
                int rb = (qq * 256 + w * 64 + f * 32 + lr) * 8;
                ah[f]  = *(const short8*)&sAh[ra];
                al[f]  = *(const short8*)&sAl[ra];
                bhf[f] = *(const short8*)&sBh[rb];
                blf[f] = *(const short8*)&sBl[rb];
            }
            #pragma unroll
            for (int fm = 0; fm < 2; ++fm)
                #pragma unroll
                for (int fn = 0; fn < 2; ++fn)
                    mfma_bf16(acc[fm][fn], ah[fm], bhf[fn]);
            #pragma unroll
            for (int fm = 0; fm < 2; ++fm)
                #pragma unroll
                for (int fn = 0; fn < 2; ++fn)
                    mfma_bf16(acc[fm][fn], ah[fm], blf[fn]);
            #pragma unroll
            for (int fm = 0; fm < 2; ++fm)
                #pragma unroll
                for (int fn = 0; fn < 2; ++fn)
                    mfma_bf16(acc[fm][fn], al[fm], bhf[fn]);
        }
        asm volatile("s_waitcnt lgkmcnt(0)" ::: "memory");
        __builtin_amdgcn_s_barrier();             // all waves done reading buf[cur]
        if (it < 30)
            g2_stage(Ahg, Alg, CAB,
                     Ah[cur], Al[cur], Bh[cur], Bl[cur], t, m0, n0, (it + 2) * 32);
        cur ^= 1;
    }
    #pragma unroll
    for (int fm = 0; fm < 2; ++fm)
        #pragma unroll
        for (int fn = 0; fn < 2; ++fn) {
            int colb = n0 + w * 64 + fn * 32 + lr;
            int rowb = m0 + fm * 32 + 4 * lk;
            #pragma unroll
            for (int r = 0; r < 16; ++r) {
                int row = rowb + (r & 3) + 8 * (r >> 2);
                C[(size_t)row * HW_ + colb] = acc[fm][fn][r];
            }
        }
}

// ---------------------------------------------------------------------------
// Final: ACL scatter (9 taps of ET), mask blend, 1x1 conv + bias + ELU.
// 256 blocks x 256 threads; thread = (channel-quarter, pixel). 4 waves/CU.
// Gathers are duplicated across the 4 quarters of a pixel but L1-resident.
// ---------------------------------------------------------------------------
__global__ __launch_bounds__(256) void final_kernel(const float* __restrict__ ET,
                                                    const float* __restrict__ bg_in,
                                                    const float* __restrict__ mask,
                                                    const float* __restrict__ fw,
                                                    const float* __restrict__ fb,
                                                    float* __restrict__ out) {
    __shared__ float fwT[128 * 64];               // fwT[c2][c] = fw[c*128 + c2]
    #pragma unroll
    for (int i = 0; i < 32; ++i) {
        int lin = i * 256 + threadIdx.x;
        int c = lin >> 7, c2 = lin & 127;
        fwT[(c2 << 6) + c] = fw[lin];
    }
    __syncthreads();

    int qc = threadIdx.x >> 6;                    // channel quarter 0..3 (wave-uniform)
    int px = threadIdx.x & 63;
    int gp = blockIdx.x * 64 + px;                // b*4096 + p
    int b = gp >> 12, p = gp & 4095;
    int y = p >> 6, x = p & 63;
    const float* bgp = bg_in + ((size_t)(b * C_) << 12) + p;
    const float* Eb  = ET + (size_t)b * D_ * HW_;
    float m = mask[gp];
    int c0 = qc << 4;

    float acc[16];
    #pragma unroll
    for (int c = 0; c < 16; ++c) acc[c] = fb[c0 + c];

    for (int c2 = 0; c2 < 64; ++c2) {
        float bgv = bgp[(size_t)c2 << 12];
        float a = 0.f;
        if (m == 0.f) {
            #pragma unroll
            for (int kk = 0; kk < 9; ++kk) {
                int i = kk / 3, j = kk - (kk / 3) * 3;
                int hh = y + 1 - i, ww2 = x + 1 - j;
                if ((unsigned)hh < 64u && (unsigned)ww2 < 64u)
                    a += Eb[(size_t)(c2 * 9 + kk) * HW_ + (hh << 6) + ww2];
            }
            a *= (1.f / 9.f);
        }
        float aclv = (m != 0.f) ? bgv : a;
        const float* f1 = &fwT[(c2 << 6) + c0];        // broadcast reads (free)
        const float* f2 = &fwT[((64 + c2) << 6) + c0];
        #pragma unroll
        for (int c4 = 0; c4 < 4; ++c4) {
            float4 fa  = *(const float4*)&f1[c4 << 2];
            float4 fb4 = *(const float4*)&f2[c4 << 2];
            acc[(c4 << 2) + 0] += fa.x * bgv + fb4.x * aclv;
            acc[(c4 << 2) + 1] += fa.y * bgv + fb4.y * aclv;
            acc[(c4 << 2) + 2] += fa.z * bgv + fb4.z * aclv;
            acc[(c4 << 2) + 3] += fa.w * bgv + fb4.w * aclv;
        }
    }
    float* op = out + ((size_t)(b * C_) << 12) + p;
    #pragma unroll
    for (int c = 0; c < 16; ++c) {
        float v = acc[c];
        op[(size_t)(c0 + c) << 12] = v > 0.f ? v : expm1f(v);
    }
}

extern "C" void kernel_launch(void* const* d_in, const int* in_sizes, int n_in,
                              void* d_out, int out_size, void* d_ws, size_t ws_size,
                              hipStream_t stream) {
    const float* bg_in  = (const float*)d_in[0];
    const float* fg_in  = (const float*)d_in[1];
    const float* mask   = (const float*)d_in[2];
    const float* fuse_w = (const float*)d_in[3];
    const float* fuse_b = (const float*)d_in[4];
    float* out = (float*)d_out;

    char* base = (char*)d_ws;
    u16* WWh  = (u16*)base;  base += (size_t)B_ * HW_ * D_ * 2;
    u16* WWl  = (u16*)base;  base += (size_t)B_ * HW_ * D_ * 2;
    u16* UBh  = (u16*)base;  base += (size_t)B_ * D_ * LP_ * 2;
    u16* UBl  = (u16*)base;  base += (size_t)B_ * D_ * LP_ * 2;
    u16* UBTh = (u16*)base;  base += (size_t)B_ * LP_ * D_ * 2;
    u16* UBTl = (u16*)base;  base += (size_t)B_ * LP_ * D_ * 2;
    float* CS  = (float*)base;  base += (size_t)B_ * HW_ * LP_ * 4;
    float* K1D = (float*)base;  base += (size_t)B_ * LP_ * 4;
    float* P   = (float*)base;  base += (size_t)B_ * HW_ * 4;
    float* ET  = (float*)WWh;   // alias: WW dead after GEMM1

    hipMemsetAsync(K1D, 0, (size_t)B_ * LP_ * sizeof(float), stream);
    fill_ub_kernel <<<(B_ * D_ * LP_) / 256, 256, 0, stream>>>(bg_in, mask, UBh, UBl);
    fill_ubT_kernel<<<(B_ * LP_ * D_) / 256, 256, 0, stream>>>(bg_in, mask, UBTh, UBTl);
    k1d_kernel<<<dim3((B_ * LP_) / 256, 4), 256, 0, stream>>>(UBh, UBl, K1D);
    fill_ww_kernel<<<(B_ * HW_ * D_) / 256, 256, 0, stream>>>(fg_in, WWh, WWl);
    pixsq_kernel<<<(B_ * HW_) / 256, 256, 0, stream>>>(fg_in, P);
    gemm1_kernel<<<dim3(LP_ / 128, HW_ / 128, B_), 256, 0, stream>>>(WWh, WWl, UBTh, UBTl, CS);
    stats_softmax_kernel<<<B_ * HW_, 256, 0, stream>>>(CS, K1D, P);
    gemm2_kernel<<<dim3(HW_ / 256, D_ / 64, B_), 256, 0, stream>>>(UBh, UBl, CS, ET);
    final_kernel<<<(B_ * HW_) / 64, 256, 0, stream>>>(ET, bg_in, mask, fuse_w, fuse_b, out);
}

// Round 10
// 561.165 us; speedup vs baseline: 1.1897x; 1.1217x over previous
//
#include <hip/hip_runtime.h>

#define B_   4
#define C_   64
#define HW_  4096
#define D_   576      // C * 3 * 3
#define L_   961      // 31 * 31 keys
#define LP_  1024     // padded L (zero-filled)
#define LAMDA_ 10.0f
#define EPS_   1e-6f

typedef short short8 __attribute__((ext_vector_type(8)));
typedef float f32x16 __attribute__((ext_vector_type(16)));
typedef unsigned short u16;

// round-to-nearest-even f32 -> bf16 bits
__device__ __forceinline__ u16 f2bf(float x) {
    unsigned u = __float_as_uint(x);
    u += 0x7FFFu + ((u >> 16) & 1u);
    return (u16)(u >> 16);
}
__device__ __forceinline__ float bf2f(u16 h) {
    return __uint_as_float(((unsigned)h) << 16);
}
__device__ __forceinline__ void mfma_bf16(f32x16& d, short8 a, short8 b) {
    asm volatile("v_mfma_f32_32x32x16_bf16 %0, %1, %2, %0"
                 : "+v"(d) : "v"(a), "v"(b));
}

// Direct global->LDS 16B load. LDS dest must be wave-uniform base + lane*16
// (our staging slot order satisfies this by construction).
__device__ __forceinline__ void gl16(const u16* g, u16* l) {
#if defined(__has_builtin) && __has_builtin(__builtin_amdgcn_global_load_lds)
    __builtin_amdgcn_global_load_lds(
        (const __attribute__((address_space(1))) unsigned int*)g,
        (__attribute__((address_space(3))) unsigned int*)l, 16, 0, 0);
#else
    *(uint4*)l = *(const uint4*)g;
#endif
}

// ---------------------------------------------------------------------------
// UB[b][d][l] (d-major) hi/lo: ub = bg_in*mask unfolded (k=3, s=2, pad=0)
// ---------------------------------------------------------------------------
__global__ __launch_bounds__(256) void fill_ub_kernel(const float* __restrict__ bg_in,
                                                      const float* __restrict__ mask,
                                                      u16* __restrict__ UBh,
                                                      u16* __restrict__ UBl) {
    int idx = blockIdx.x * 256 + threadIdx.x;     // b*D_*LP_ + d*LP_ + l
    int b   = idx / (D_ * LP_);
    int rem = idx - b * (D_ * LP_);
    int d   = rem >> 10;
    int l   = idx & (LP_ - 1);
    float v = 0.f;
    if (l < L_) {
        int ly = l / 31, lx = l - ly * 31;
        int c  = d / 9,  kk = d - c * 9;
        int i  = kk / 3, j  = kk - i * 3;
        int pix = ((2 * ly + i) << 6) + 2 * lx + j;
        v = bg_in[((b * C_ + c) << 12) + pix] * mask[(b << 12) + pix];
    }
    u16 h = f2bf(v);
    UBh[idx] = h;
    UBl[idx] = f2bf(v - bf2f(h));
}

// UBT[b][l][d] (l-major) hi/lo — same values, transposed layout for GEMM1 B.
__global__ __launch_bounds__(256) void fill_ubT_kernel(const float* __restrict__ bg_in,
                                                       const float* __restrict__ mask,
                                                       u16* __restrict__ UBTh,
                                                       u16* __restrict__ UBTl) {
    int idx = blockIdx.x * 256 + threadIdx.x;     // (b*LP_ + l)*D_ + d
    int d   = idx % D_;
    int tmp = idx / D_;
    int l   = tmp & (LP_ - 1);
    int b   = tmp >> 10;
    float v = 0.f;
    if (l < L_) {
        int ly = l / 31, lx = l - ly * 31;
        int c  = d / 9,  kk = d - c * 9;
        int i  = kk / 3, j  = kk - i * 3;
        int pix = ((2 * ly + i) << 6) + 2 * lx + j;
        v = bg_in[((b * C_ + c) << 12) + pix] * mask[(b << 12) + pix];
    }
    u16 h = f2bf(v);
    UBTh[idx] = h;
    UBTl[idx] = f2bf(v - bf2f(h));
}

// K1D[b][l] += partial sum over 144 d's of (hi+lo)^2
__global__ __launch_bounds__(256) void k1d_kernel(const u16* __restrict__ UBh,
                                                  const u16* __restrict__ UBl,
                                                  float* __restrict__ K1D) {
    int t = blockIdx.x * 256 + threadIdx.x;       // b*1024 + l
    int b = t >> 10;
    int l = t & 1023;
    size_t base = (size_t)b * (D_ * LP_) + (size_t)(blockIdx.y * 144) * LP_ + l;
    float s = 0.f;
    #pragma unroll 8
    for (int d = 0; d < 144; ++d) {
        float v = bf2f(UBh[base + (size_t)d * LP_]) + bf2f(UBl[base + (size_t)d * LP_]);
        s += v * v;
    }
    atomicAdd(&K1D[t], s);
}

// WW[b][p][d] hi/lo = fg unfolded (k=3, s=1, pad=1) — query patches
__global__ __launch_bounds__(256) void fill_ww_kernel(const float* __restrict__ fg,
                                                      u16* __restrict__ WWh,
                                                      u16* __restrict__ WWl) {
    int idx = blockIdx.x * 256 + threadIdx.x;     // (b*HW + p)*D + d
    int d   = idx % D_;
    int tmp = idx / D_;
    int p   = tmp & 4095;
    int b   = tmp >> 12;
    int c   = d / 9,  kk = d - c * 9;
    int i   = kk / 3, j  = kk - i * 3;
    int y   = (p >> 6) + i - 1, x = (p & 63) + j - 1;
    float v = 0.f;
    if ((unsigned)y < 64u && (unsigned)x < 64u)
        v = fg[((b * C_ + c) << 12) + (y << 6) + x];
    u16 h = f2bf(v);
    WWh[idx] = h;
    WWl[idx] = f2bf(v - bf2f(h));
}

// P[b][p] = sum_c fg^2 (exact f32)
__global__ __launch_bounds__(256) void pixsq_kernel(const float* __restrict__ fg,
                                                    float* __restrict__ P) {
    int t = blockIdx.x * 256 + threadIdx.x;
    int b = t >> 12, p = t & 4095;
    const float* base = fg + ((size_t)(b * C_) << 12) + p;
    float s = 0.f;
    #pragma unroll 8
    for (int c = 0; c < C_; ++c) { float v = base[c << 12]; s += v * v; }
    P[t] = s;
}

// ---------------------------------------------------------------------------
// GEMM1: CS[b][q][l] = sum_d WW[q][d]*UB[d][l], bf16x3 MFMA 32x32x16.
// Block 128x128, 4 waves (2x2). Single-buffered BK=32, 32KB LDS ->
// grid 1024 blocks = 4 blocks/CU (~16 waves): drain hidden by other blocks.
// ---------------------------------------------------------------------------
__global__ __launch_bounds__(256) void gemm1_kernel(
    const u16* __restrict__ WWh, const u16* __restrict__ WWl,
    const u16* __restrict__ UBTh, const u16* __restrict__ UBTl,
    float* __restrict__ CS)
{
    int b = blockIdx.z;
    const u16* Ahg = WWh  + (size_t)b * HW_ * D_;
    const u16* Alg = WWl  + (size_t)b * HW_ * D_;
    const u16* Bhg = UBTh + (size_t)b * LP_ * D_;
    const u16* Blg = UBTl + (size_t)b * LP_ * D_;
    float* C = CS + (size_t)b * HW_ * LP_;
    int n0 = blockIdx.x << 7, m0 = blockIdx.y << 7;

    __shared__ __align__(16) u16 Ah[4096], Al[4096], Bh[4096], Bl[4096];  // 8KB each

    int t = threadIdx.x;
    int lane = t & 63;
    int w = t >> 6, wm = w >> 1, wn = w & 1;
    int lr = lane & 31, lk = lane >> 5;

    f32x16 acc[2][2];
    #pragma unroll
    for (int i = 0; i < 2; ++i)
        #pragma unroll
        for (int j = 0; j < 2; ++j)
            #pragma unroll
            for (int r = 0; r < 16; ++r) acc[i][j][r] = 0.f;

    for (int k0 = 0; k0 < D_; k0 += 32) {
        #pragma unroll
        for (int i = 0; i < 2; ++i) {             // 512 16B slots per matrix
            int lin = i * 256 + t;
            int q = lin >> 7, r = lin & 127;
            size_t ga = (size_t)(m0 + r) * D_ + k0 + q * 8;
            size_t gb = (size_t)(n0 + r) * D_ + k0 + q * 8;
            gl16(Ahg + ga, Ah + lin * 8);
            gl16(Alg + ga, Al + lin * 8);
            gl16(Bhg + gb, Bh + lin * 8);
            gl16(Blg + gb, Bl + lin * 8);
        }
        __syncthreads();                          // drains vmcnt: tile ready
        #pragma unroll
        for (int kh = 0; kh < 2; ++kh) {
            int qq = kh * 2 + lk;
            short8 ah[2], al[2], bhf[2], blf[2];
            #pragma unroll
            for (int f = 0; f < 2; ++f) {
                int ra = (qq * 128 + wm * 64 + f * 32 + lr) * 8;
                int rb = (qq * 128 + wn * 64 + f * 32 + lr) * 8;
                ah[f]  = *(const short8*)&Ah[ra];
                al[f]  = *(const short8*)&Al[ra];
                bhf[f] = *(const short8*)&Bh[rb];
                blf[f] = *(const short8*)&Bl[rb];
            }
            #pragma unroll
            for (int fm = 0; fm < 2; ++fm)
                #pragma unroll
                for (int fn = 0; fn < 2; ++fn)
                    mfma_bf16(acc[fm][fn], ah[fm], bhf[fn]);
            #pragma unroll
            for (int fm = 0; fm < 2; ++fm)
                #pragma unroll
                for (int fn = 0; fn < 2; ++fn)
                    mfma_bf16(acc[fm][fn], ah[fm], blf[fn]);
            #pragma unroll
            for (int fm = 0; fm < 2; ++fm)
                #pragma unroll
                for (int fn = 0; fn < 2; ++fn)
                    mfma_bf16(acc[fm][fn], al[fm], bhf[fn]);
        }
        __syncthreads();                          // all reads done before overwrite
    }
    #pragma unroll
    for (int fm = 0; fm < 2; ++fm)
        #pragma unroll
        for (int fn = 0; fn < 2; ++fn) {
            int colb = n0 + wn * 64 + fn * 32 + lr;
            int rowb = m0 + wm * 64 + fm * 32 + 4 * lk;
            #pragma unroll
            for (int r = 0; r < 16; ++r) {
                int row = rowb + (r & 3) + 8 * (r >> 2);
                C[(size_t)row * LP_ + colb] = acc[fm][fn][r];
            }
        }
}

// ---------------------------------------------------------------------------
// Row stats + tanh + softmax. Reads f32 CS row, writes bf16 hi/lo IN PLACE.
// ---------------------------------------------------------------------------
__device__ __forceinline__ float block_reduce_sum(float v, float* sred) {
    #pragma unroll
    for (int m = 32; m > 0; m >>= 1) v += __shfl_xor(v, m, 64);
    __syncthreads();
    if ((threadIdx.x & 63) == 0) sred[threadIdx.x >> 6] = v;
    __syncthreads();
    return sred[0] + sred[1] + sred[2] + sred[3];
}

__global__ __launch_bounds__(256) void stats_softmax_kernel(float* __restrict__ CA,
                                                            const float* __restrict__ K1D,
                                                            const float* __restrict__ P) {
    __shared__ float sred[4];
    int row = blockIdx.x;                         // b*4096 + q
    int b = row >> 12, q = row & 4095;
    int h = q >> 6, wx = q & 63;
    float wwd = 0.f;
    #pragma unroll
    for (int i = 0; i < 3; ++i)
        #pragma unroll
        for (int j = 0; j < 3; ++j) {
            int y = h + i - 1, x = wx + j - 1;
            if ((unsigned)y < 64u && (unsigned)x < 64u)
                wwd += P[(b << 12) + (y << 6) + x];
        }
    float* cs = CA + (size_t)row * LP_;
    u16* ch = (u16*)cs;                           // in-place overlay
    const float* k1 = K1D + (b << 10);
    int t = threadIdx.x;
    float xv[4];
    float lsum = 0.f;
    #pragma unroll
    for (int i = 0; i < 4; ++i) {
        int l = t + (i << 8);
        float ds = 0.f;
        if (l < L_) ds = k1[l] + wwd - 2.f * cs[l];
        xv[i] = ds;
        lsum += ds;
    }
    float mean = block_reduce_sum(lsum, sred) * (1.f / 961.f);
    float lvar = 0.f;
    #pragma unroll
    for (int i = 0; i < 4; ++i) {
        int l = t + (i << 8);
        if (l < L_) { float dd = xv[i] - mean; lvar += dd * dd; }
    }
    float var = block_reduce_sum(lvar, sred) * (1.f / 961.f);
    float inv = 1.f / (sqrtf(var) + EPS_);
    float ev[4];
    float lsume = 0.f;
    #pragma unroll
    for (int i = 0; i < 4; ++i) {
        int l = t + (i << 8);
        float e = 0.f;
        if (l < L_) e = expf(-LAMDA_ * tanhf((xv[i] - mean) * inv));
        ev[i] = e;
        lsume += e;
    }
    float rs = 1.f / block_reduce_sum(lsume, sred);
    #pragma unroll
    for (int i = 0; i < 4; ++i) {                 // all reads done (barriers above)
        int l2 = t + (i << 8);
        float v = ev[i] * rs;                     // pad -> exact 0
        u16 hi = f2bf(v);
        ch[l2]        = hi;
        ch[1024 + l2] = f2bf(v - bf2f(hi));
    }
}

// ---------------------------------------------------------------------------
// GEMM2: ET[b][d][q] = sum_l UB[d][l]*CA[q][l], bf16x3 MFMA (NT).
// Block 64m x 128n, 4 waves (1x4): wave = 64x32 (2x1 frags of 32x32).
// Grid 32x9x4 = 1152 blocks (~4.5/CU); 24KB LDS, single-buffered BK=32.
// TLP doubled vs the 256-wide tile (grid was the occupancy limiter).
// ---------------------------------------------------------------------------
__global__ __launch_bounds__(256) void gemm2_kernel(
    const u16* __restrict__ UBh, const u16* __restrict__ UBl,
    const float* __restrict__ CAbase, float* __restrict__ ET)
{
    int b = blockIdx.z;
    const u16* Ahg = UBh + (size_t)b * D_ * LP_;
    const u16* Alg = UBl + (size_t)b * D_ * LP_;
    const u16* CAB = (const u16*)(CAbase + (size_t)b * HW_ * LP_);   // rows: 2048 u16
    float* C = ET + (size_t)b * D_ * HW_;
    int n0 = blockIdx.x << 7, m0 = blockIdx.y << 6;

    __shared__ __align__(16) u16 Ah[2048], Al[2048], Bh[4096], Bl[4096];  // 24 KB

    int t = threadIdx.x;
    int lane = t & 63;
    int w = t >> 6;                               // wave 0..3 -> n-offset w*32
    int lr = lane & 31, lk = lane >> 5;

    f32x16 acc[2];                                // 2 m-frags x 1 n-frag
    #pragma unroll
    for (int i = 0; i < 2; ++i)
        #pragma unroll
        for (int r = 0; r < 16; ++r) acc[i][r] = 0.f;

    for (int k0 = 0; k0 < LP_; k0 += 32) {
        {                                         // A: 256 slots (64 rows x 4 chunks)
            int q = t >> 6, r = t & 63;
            size_t ga = (size_t)(m0 + r) * LP_ + k0 + q * 8;
            gl16(Ahg + ga, Ah + t * 8);
            gl16(Alg + ga, Al + t * 8);
        }
        #pragma unroll
        for (int i = 0; i < 2; ++i) {             // B: 512 slots (128 rows x 4 chunks)
            int lin = i * 256 + t;
            int q = lin >> 7, r = lin & 127;
            size_t gb = (size_t)(n0 + r) * 2048 + k0 + q * 8;
            gl16(CAB + gb,        Bh + lin * 8);
            gl16(CAB + gb + 1024, Bl + lin * 8);
        }
        __syncthreads();                          // tile ready
        #pragma unroll
        for (int kh = 0; kh < 2; ++kh) {
            int qq = kh * 2 + lk;
            short8 ah[2], al[2], bhf, blf;
            #pragma unroll
            for (int f = 0; f < 2; ++f) {
                int ra = (qq * 64 + f * 32 + lr) * 8;
                ah[f] = *(const short8*)&Ah[ra];
                al[f] = *(const short8*)&Al[ra];
            }
            {
                int rb = (qq * 128 + w * 32 + lr) * 8;
                bhf = *(const short8*)&Bh[rb];
                blf = *(const short8*)&Bl[rb];
            }
            #pragma unroll
            for (int fm = 0; fm < 2; ++fm) mfma_bf16(acc[fm], ah[fm], bhf);
            #pragma unroll
            for (int fm = 0; fm < 2; ++fm) mfma_bf16(acc[fm], ah[fm], blf);
            #pragma unroll
            for (int fm = 0; fm < 2; ++fm) mfma_bf16(acc[fm], al[fm], bhf);
        }
        __syncthreads();                          // reads done before overwrite
    }
    #pragma unroll
    for (int fm = 0; fm < 2; ++fm) {
        int colb = n0 + w * 32 + lr;
        int rowb = m0 + fm * 32 + 4 * lk;
        #pragma unroll
        for (int r = 0; r < 16; ++r) {
            int row = rowb + (r & 3) + 8 * (r >> 2);
            C[(size_t)row * HW_ + colb] = acc[fm][r];
        }
    }
}

// ---------------------------------------------------------------------------
// Final: ACL scatter (9 taps of ET), mask blend, 1x1 conv + bias + ELU.
// 256 blocks x 256 threads; thread = (channel-quarter, pixel). 4 waves/CU.
// ---------------------------------------------------------------------------
__global__ __launch_bounds__(256) void final_kernel(const float* __restrict__ ET,
                                                    const float* __restrict__ bg_in,
                                                    const float* __restrict__ mask,
                                                    const float* __restrict__ fw,
                                                    const float* __restrict__ fb,
                                                    float* __restrict__ out) {
    __shared__ float fwT[128 * 64];               // fwT[c2][c] = fw[c*128 + c2]
    #pragma unroll
    for (int i = 0; i < 32; ++i) {
        int lin = i * 256 + threadIdx.x;
        int c = lin >> 7, c2 = lin & 127;
        fwT[(c2 << 6) + c] = fw[lin];
    }
    __syncthreads();

    int qc = threadIdx.x >> 6;                    // channel quarter 0..3 (wave-uniform)
    int px = threadIdx.x & 63;
    int gp = blockIdx.x * 64 + px;                // b*4096 + p
    int b = gp >> 12, p = gp & 4095;
    int y = p >> 6, x = p & 63;
    const float* bgp = bg_in + ((size_t)(b * C_) << 12) + p;
    const float* Eb  = ET + (size_t)b * D_ * HW_;
    float m = mask[gp];
    int c0 = qc << 4;

    float acc[16];
    #pragma unroll
    for (int c = 0; c < 16; ++c) acc[c] = fb[c0 + c];

    for (int c2 = 0; c2 < 64; ++c2) {
        float bgv = bgp[(size_t)c2 << 12];
        float a = 0.f;
        if (m == 0.f) {
            #pragma unroll
            for (int kk = 0; kk < 9; ++kk) {
                int i = kk / 3, j = kk - (kk / 3) * 3;
                int hh = y + 1 - i, ww2 = x + 1 - j;
                if ((unsigned)hh < 64u && (unsigned)ww2 < 64u)
                    a += Eb[(size_t)(c2 * 9 + kk) * HW_ + (hh << 6) + ww2];
            }
            a *= (1.f / 9.f);
        }
        float aclv = (m != 0.f) ? bgv : a;
        const float* f1 = &fwT[(c2 << 6) + c0];        // broadcast reads (free)
        const float* f2 = &fwT[((64 + c2) << 6) + c0];
        #pragma unroll
        for (int c4 = 0; c4 < 4; ++c4) {
            float4 fa  = *(const float4*)&f1[c4 << 2];
            float4 fb4 = *(const float4*)&f2[c4 << 2];
            acc[(c4 << 2) + 0] += fa.x * bgv + fb4.x * aclv;
            acc[(c4 << 2) + 1] += fa.y * bgv + fb4.y * aclv;
            acc[(c4 << 2) + 2] += fa.z * bgv + fb4.z * aclv;
            acc[(c4 << 2) + 3] += fa.w * bgv + fb4.w * aclv;
        }
    }
    float* op = out + ((size_t)(b * C_) << 12) + p;
    #pragma unroll
    for (int c = 0; c < 16; ++c) {
        float v = acc[c];
        op[(size_t)(c0 + c) << 12] = v > 0.f ? v : expm1f(v);
    }
}

extern "C" void kernel_launch(void* const* d_in, const int* in_sizes, int n_in,
                              void* d_out, int out_size, void* d_ws, size_t ws_size,
                              hipStream_t stream) {
    const float* bg_in  = (const float*)d_in[0];
    const float* fg_in  = (const float*)d_in[1];
    const float* mask   = (const float*)d_in[2];
    const float* fuse_w = (const float*)d_in[3];
    const float* fuse_b = (const float*)d_in[4];
    float* out = (float*)d_out;

    char* base = (char*)d_ws;
    u16* WWh  = (u16*)base;  base += (size_t)B_ * HW_ * D_ * 2;
    u16* WWl  = (u16*)base;  base += (size_t)B_ * HW_ * D_ * 2;
    u16* UBh  = (u16*)base;  base += (size_t)B_ * D_ * LP_ * 2;
    u16* UBl  = (u16*)base;  base += (size_t)B_ * D_ * LP_ * 2;
    u16* UBTh = (u16*)base;  base += (size_t)B_ * LP_ * D_ * 2;
    u16* UBTl = (u16*)base;  base += (size_t)B_ * LP_ * D_ * 2;
    float* CS  = (float*)base;  base += (size_t)B_ * HW_ * LP_ * 4;
    float* K1D = (float*)base;  base += (size_t)B_ * LP_ * 4;
    float* P   = (float*)base;  base += (size_t)B_ * HW_ * 4;
    float* ET  = (float*)WWh;   // alias: WW dead after GEMM1

    hipMemsetAsync(K1D, 0, (size_t)B_ * LP_ * sizeof(float), stream);
    fill_ub_kernel <<<(B_ * D_ * LP_) / 256, 256, 0, stream>>>(bg_in, mask, UBh, UBl);
    fill_ubT_kernel<<<(B_ * LP_ * D_) / 256, 256, 0, stream>>>(bg_in, mask, UBTh, UBTl);
    k1d_kernel<<<dim3((B_ * LP_) / 256, 4), 256, 0, stream>>>(UBh, UBl, K1D);
    fill_ww_kernel<<<(B_ * HW_ * D_) / 256, 256, 0, stream>>>(fg_in, WWh, WWl);
    pixsq_kernel<<<(B_ * HW_) / 256, 256, 0, stream>>>(fg_in, P);
    gemm1_kernel<<<dim3(LP_ / 128, HW_ / 128, B_), 256, 0, stream>>>(WWh, WWl, UBTh, UBTl, CS);
    stats_softmax_kernel<<<B_ * HW_, 256, 0, stream>>>(CS, K1D, P);
    gemm2_kernel<<<dim3(HW_ / 128, D_ / 64, B_), 256, 0, stream>>>(UBh, UBl, CS, ET);
    final_kernel<<<(B_ * HW_) / 64, 256, 0, stream>>>(ET, bg_in, mask, fuse_w, fuse_b, out);
}